// Round 1
// baseline (2359.048 us; speedup 1.0000x reference)
//
#include <hip/hip_runtime.h>
#include <cstdint>
#include <cstddef>

#define NNODES 100000
#define NGRAPHS 128
#define NEG_SLOPE 0.2f

// ---------- float atomic max via monotone uint mapping ----------
static __device__ __forceinline__ void atomicMaxF(unsigned int* addr, float val) {
    unsigned int uv = __float_as_uint(val);
    uv = (uv & 0x80000000u) ? ~uv : (uv | 0x80000000u);
    atomicMax(addr, uv);
}

// decode mapped-max back to float bits, in place (one thread per element)
__global__ void decode_max_kernel(unsigned int* m, int n) {
    int i = blockIdx.x * blockDim.x + threadIdx.x;
    if (i >= n) return;
    unsigned int u = m[i];
    unsigned int bits = (u & 0x80000000u) ? (u & 0x7fffffffu) : ~u;
    m[i] = bits;
}

// ---------- GEMM: C[M,N] = A[M,K] @ B[K,N], row-major ----------
// BM=BN=64, BK=16, 256 threads, 4x4 register tile per thread.
#define BM 64
#define BN 64
#define BK 16
__global__ void gemm_kernel(const float* __restrict__ A, const float* __restrict__ B,
                            float* __restrict__ C, int M, int K, int N) {
    __shared__ float As[BK][BM + 1];
    __shared__ float Bs[BK][BN + 1];
    int tid = threadIdx.x;
    int tx = tid & 15;   // N dir
    int ty = tid >> 4;   // M dir
    int row0 = blockIdx.y * BM;
    int col0 = blockIdx.x * BN;

    float acc[4][4] = {};

    for (int k0 = 0; k0 < K; k0 += BK) {
        // load A tile: 64 rows x 16 k = 1024 elems, 4 per thread (consecutive k)
        {
            int r  = tid >> 2;              // 0..63
            int kb = (tid & 3) * 4;         // 0,4,8,12
            int grow = row0 + r;
            #pragma unroll
            for (int u = 0; u < 4; ++u) {
                float v = 0.f;
                if (grow < M) v = A[(size_t)grow * K + k0 + kb + u];
                As[kb + u][r] = v;
            }
        }
        // load B tile: 16 k x 64 cols, 4 per thread (consecutive cols)
        {
            int kk = tid >> 4;              // 0..15
            int cb = (tid & 15) * 4;        // 0..60
            #pragma unroll
            for (int u = 0; u < 4; ++u) {
                Bs[kk][cb + u] = B[(size_t)(k0 + kk) * N + col0 + cb + u];
            }
        }
        __syncthreads();
        #pragma unroll
        for (int kk = 0; kk < BK; ++kk) {
            float a[4], b[4];
            #pragma unroll
            for (int i = 0; i < 4; ++i) a[i] = As[kk][ty * 4 + i];
            #pragma unroll
            for (int j = 0; j < 4; ++j) b[j] = Bs[kk][tx * 4 + j];
            #pragma unroll
            for (int i = 0; i < 4; ++i)
                #pragma unroll
                for (int j = 0; j < 4; ++j)
                    acc[i][j] += a[i] * b[j];
        }
        __syncthreads();
    }

    #pragma unroll
    for (int i = 0; i < 4; ++i) {
        int row = row0 + ty * 4 + i;
        if (row >= M) continue;
        #pragma unroll
        for (int j = 0; j < 4; ++j) {
            int col = col0 + tx * 4 + j;
            if (col < N) C[(size_t)row * N + col] = acc[i][j];
        }
    }
}

// ---------- per-node attention coefficients: a_src[n,h], a_dst[n,h] ----------
__global__ void att_node_kernel(const float* __restrict__ xw,
                                const float* __restrict__ att_src,
                                const float* __restrict__ att_dst,
                                float* __restrict__ asrc, float* __restrict__ adst) {
    int idx = blockIdx.x * blockDim.x + threadIdx.x;
    if (idx >= NNODES * 2) return;
    int n = idx >> 1, h = idx & 1;
    const float* row = xw + (size_t)n * 128 + h * 64;
    const float* as = att_src + h * 64;
    const float* ad = att_dst + h * 64;
    float s1 = 0.f, s2 = 0.f;
    for (int c = 0; c < 64; ++c) {
        float v = row[c];
        s1 += v * as[c];
        s2 += v * ad[c];
    }
    asrc[idx] = s1;
    adst[idx] = s2;
}

// ---------- per-edge logits + segment max ----------
__global__ void edge_logits_max_kernel(const int* __restrict__ src, const int* __restrict__ dst,
                                       const float* __restrict__ asrc, const float* __restrict__ adst,
                                       float* __restrict__ elog, unsigned int* __restrict__ m,
                                       int E, int ET) {
    int e = blockIdx.x * blockDim.x + threadIdx.x;
    if (e >= ET) return;
    int s = (e < E) ? src[e] : (e - E);
    int d = (e < E) ? dst[e] : (e - E);
    #pragma unroll
    for (int h = 0; h < 2; ++h) {
        float l = asrc[s * 2 + h] + adst[d * 2 + h];
        l = (l > 0.f) ? l : NEG_SLOPE * l;
        elog[(size_t)e * 2 + h] = l;
        atomicMaxF(&m[d * 2 + h], l);
    }
}

// ---------- per-edge exp + segment sum ----------
__global__ void edge_exp_kernel(const int* __restrict__ src, const int* __restrict__ dst,
                                float* __restrict__ elog, const unsigned int* __restrict__ m,
                                float* __restrict__ ssum, int E, int ET) {
    int e = blockIdx.x * blockDim.x + threadIdx.x;
    if (e >= ET) return;
    int d = (e < E) ? dst[e] : (e - E);
    #pragma unroll
    for (int h = 0; h < 2; ++h) {
        float mx = __uint_as_float(m[d * 2 + h]);
        float ex = expf(elog[(size_t)e * 2 + h] - mx);
        elog[(size_t)e * 2 + h] = ex;
        atomicAdd(&ssum[d * 2 + h], ex);
    }
}

// ---------- per-edge weighted scatter: acc[dst] += alpha * xw[src] ----------
__global__ void edge_aggregate_kernel(const int* __restrict__ src, const int* __restrict__ dst,
                                      const float* __restrict__ elog, const float* __restrict__ ssum,
                                      const float* __restrict__ xw, float* __restrict__ acc,
                                      int E, int ET) {
    size_t idx = (size_t)blockIdx.x * blockDim.x + threadIdx.x;
    size_t total = (size_t)ET * 128;
    if (idx >= total) return;
    int e = (int)(idx >> 7);
    int j = (int)(idx & 127);
    int s = (e < E) ? src[e] : (e - E);
    int d = (e < E) ? dst[e] : (e - E);
    int h = j >> 6;
    float alpha = elog[(size_t)e * 2 + h] / (ssum[d * 2 + h] + 1e-16f);
    atomicAdd(&acc[(size_t)d * 128 + j], alpha * xw[(size_t)s * 128 + j]);
}

// ---------- head mean + bias + relu ----------
__global__ void node_finalize_kernel(const float* __restrict__ acc, const float* __restrict__ bias,
                                     float* __restrict__ hout) {
    int idx = blockIdx.x * blockDim.x + threadIdx.x;
    if (idx >= NNODES * 64) return;
    int n = idx >> 6, c = idx & 63;
    float v = 0.5f * (acc[(size_t)n * 128 + c] + acc[(size_t)n * 128 + 64 + c]) + bias[c];
    hout[idx] = (v > 0.f) ? v : 0.f;
}

// ---------- global add pool ----------
__global__ void pool_kernel(const float* __restrict__ h, const int* __restrict__ batch,
                            float* __restrict__ g) {
    int idx = blockIdx.x * blockDim.x + threadIdx.x;
    if (idx >= NNODES * 64) return;
    int n = idx >> 6, c = idx & 63;
    atomicAdd(&g[batch[n] * 64 + c], h[idx]);
}

// ---------- final FC + log_softmax ----------
__global__ void final_fc_kernel(const float* __restrict__ g, const float* __restrict__ Wfc,
                                const float* __restrict__ bfc, float* __restrict__ out) {
    int gi = threadIdx.x;
    if (gi >= NGRAPHS) return;
    float logit[10];
    #pragma unroll
    for (int o = 0; o < 10; ++o) logit[o] = bfc[o];
    for (int c = 0; c < 64; ++c) {
        float gv = g[gi * 64 + c];
        #pragma unroll
        for (int o = 0; o < 10; ++o) logit[o] += gv * Wfc[c * 10 + o];
    }
    float mx = logit[0];
    #pragma unroll
    for (int o = 1; o < 10; ++o) mx = fmaxf(mx, logit[o]);
    float se = 0.f;
    #pragma unroll
    for (int o = 0; o < 10; ++o) se += expf(logit[o] - mx);
    float lse = mx + logf(se);
    #pragma unroll
    for (int o = 0; o < 10; ++o) out[gi * 10 + o] = logit[o] - lse;
}

extern "C" void kernel_launch(void* const* d_in, const int* in_sizes, int n_in,
                              void* d_out, int out_size, void* d_ws, size_t ws_size,
                              hipStream_t stream) {
    const float* x        = (const float*)d_in[0];
    const float* W1       = (const float*)d_in[1];
    const float* att_src1 = (const float*)d_in[2];
    const float* att_dst1 = (const float*)d_in[3];
    const float* b1       = (const float*)d_in[4];
    const float* W2       = (const float*)d_in[5];
    const float* att_src2 = (const float*)d_in[6];
    const float* att_dst2 = (const float*)d_in[7];
    const float* b2       = (const float*)d_in[8];
    const float* Wfc      = (const float*)d_in[9];
    const float* bfc      = (const float*)d_in[10];
    const int*   eidx     = (const int*)d_in[11];
    const int*   batch    = (const int*)d_in[12];
    float* out = (float*)d_out;

    const int E  = in_sizes[11] / 2;
    const int ET = E + NNODES;
    const int* srcp = eidx;
    const int* dstp = eidx + E;

    // workspace layout
    float* p = (float*)d_ws;
    float* xw   = p; p += (size_t)NNODES * 128;
    float* asrc = p; p += NNODES * 2;
    float* adst = p; p += NNODES * 2;
    float* elog = p; p += (size_t)ET * 2;
    unsigned int* m = (unsigned int*)p; p += NNODES * 2;
    float* ssum = p; p += NNODES * 2;
    float* acc  = p; p += (size_t)NNODES * 128;
    float* h1   = p; p += (size_t)NNODES * 64;
    float* h2   = p; p += (size_t)NNODES * 64;
    float* g    = p; p += NGRAPHS * 64;

    const int BLK = 256;
    dim3 gemm_grid(128 / BN, (NNODES + BM - 1) / BM);
    int grid_n2   = (NNODES * 2 + BLK - 1) / BLK;
    int grid_n64  = (NNODES * 64 + BLK - 1) / BLK;
    int grid_et   = (ET + BLK - 1) / BLK;
    size_t agg_total = (size_t)ET * 128;
    int grid_agg  = (int)((agg_total + BLK - 1) / BLK);

    const float* layer_in[2]   = {x, nullptr};
    const float* layer_W[2]    = {W1, W2};
    const float* layer_as[2]   = {att_src1, att_src2};
    const float* layer_ad[2]   = {att_dst1, att_dst2};
    const float* layer_b[2]    = {b1, b2};
    float*       layer_out[2]  = {h1, h2};
    int          layer_K[2]    = {128, 64};

    for (int L = 0; L < 2; ++L) {
        const float* in_feat = (L == 0) ? x : h1;
        // xw = in_feat @ W
        gemm_kernel<<<gemm_grid, BLK, 0, stream>>>(in_feat, layer_W[L], xw, NNODES, layer_K[L], 128);
        // per-node attention coefficients
        att_node_kernel<<<grid_n2, BLK, 0, stream>>>(xw, layer_as[L], layer_ad[L], asrc, adst);
        // zero m (mapped -inf) and ssum (contiguous), zero acc
        hipMemsetAsync(m, 0, (size_t)NNODES * 4 * sizeof(float), stream);
        hipMemsetAsync(acc, 0, (size_t)NNODES * 128 * sizeof(float), stream);
        // edge logits + segment max
        edge_logits_max_kernel<<<grid_et, BLK, 0, stream>>>(srcp, dstp, asrc, adst, elog, m, E, ET);
        decode_max_kernel<<<grid_n2, BLK, 0, stream>>>(m, NNODES * 2);
        // exp + segment sum
        edge_exp_kernel<<<grid_et, BLK, 0, stream>>>(srcp, dstp, elog, m, ssum, E, ET);
        // weighted scatter
        edge_aggregate_kernel<<<grid_agg, BLK, 0, stream>>>(srcp, dstp, elog, ssum, xw, acc, E, ET);
        // head mean + bias + relu
        node_finalize_kernel<<<grid_n64, BLK, 0, stream>>>(acc, layer_b[L], layer_out[L]);
    }

    // global add pool
    hipMemsetAsync(g, 0, NGRAPHS * 64 * sizeof(float), stream);
    pool_kernel<<<grid_n64, BLK, 0, stream>>>(h2, batch, g);
    // final FC + log_softmax
    final_fc_kernel<<<1, 128, 0, stream>>>(g, Wfc, bfc, out);
}

// Round 2
// 887.000 us; speedup vs baseline: 2.6596x; 2.6596x over previous
//
#include <hip/hip_runtime.h>
#include <cstdint>
#include <cstddef>

#define NNODES 100000
#define NGRAPHS 128
#define NEG_SLOPE 0.2f

// ---------- GEMM: C[M,N] = A[M,K] @ B[K,N], row-major ----------
#define BM 64
#define BN 64
#define BK 16
__global__ void gemm_kernel(const float* __restrict__ A, const float* __restrict__ B,
                            float* __restrict__ C, int M, int K, int N) {
    __shared__ float As[BK][BM + 1];
    __shared__ float Bs[BK][BN + 1];
    int tid = threadIdx.x;
    int tx = tid & 15;   // N dir
    int ty = tid >> 4;   // M dir
    int row0 = blockIdx.y * BM;
    int col0 = blockIdx.x * BN;

    float acc[4][4] = {};

    for (int k0 = 0; k0 < K; k0 += BK) {
        {
            int r  = tid >> 2;
            int kb = (tid & 3) * 4;
            int grow = row0 + r;
            #pragma unroll
            for (int u = 0; u < 4; ++u) {
                float v = 0.f;
                if (grow < M) v = A[(size_t)grow * K + k0 + kb + u];
                As[kb + u][r] = v;
            }
        }
        {
            int kk = tid >> 4;
            int cb = (tid & 15) * 4;
            #pragma unroll
            for (int u = 0; u < 4; ++u) {
                Bs[kk][cb + u] = B[(size_t)(k0 + kk) * N + col0 + cb + u];
            }
        }
        __syncthreads();
        #pragma unroll
        for (int kk = 0; kk < BK; ++kk) {
            float a[4], b[4];
            #pragma unroll
            for (int i = 0; i < 4; ++i) a[i] = As[kk][ty * 4 + i];
            #pragma unroll
            for (int j = 0; j < 4; ++j) b[j] = Bs[kk][tx * 4 + j];
            #pragma unroll
            for (int i = 0; i < 4; ++i)
                #pragma unroll
                for (int j = 0; j < 4; ++j)
                    acc[i][j] += a[i] * b[j];
        }
        __syncthreads();
    }

    #pragma unroll
    for (int i = 0; i < 4; ++i) {
        int row = row0 + ty * 4 + i;
        if (row >= M) continue;
        #pragma unroll
        for (int j = 0; j < 4; ++j) {
            int col = col0 + tx * 4 + j;
            if (col < N) C[(size_t)row * N + col] = acc[i][j];
        }
    }
}

// ---------- per-node attention coefficients ----------
__global__ void att_node_kernel(const float* __restrict__ xw,
                                const float* __restrict__ att_src,
                                const float* __restrict__ att_dst,
                                float* __restrict__ asrc, float* __restrict__ adst) {
    int idx = blockIdx.x * blockDim.x + threadIdx.x;
    if (idx >= NNODES * 2) return;
    int n = idx >> 1, h = idx & 1;
    const float* row = xw + (size_t)n * 128 + h * 64;
    const float* as = att_src + h * 64;
    const float* ad = att_dst + h * 64;
    float s1 = 0.f, s2 = 0.f;
    for (int c = 0; c < 64; ++c) {
        float v = row[c];
        s1 += v * as[c];
        s2 += v * ad[c];
    }
    asrc[idx] = s1;
    adst[idx] = s2;
}

// ---------- CSR build ----------
__global__ void hist_kernel(const int* __restrict__ dst, int* __restrict__ deg, int E, int ET) {
    int e = blockIdx.x * blockDim.x + threadIdx.x;
    if (e >= ET) return;
    int d = (e < E) ? dst[e] : (e - E);
    atomicAdd(&deg[d], 1);
}

__global__ void scan_block_kernel(const int* __restrict__ deg, int* __restrict__ excl,
                                  int* __restrict__ psum, int n) {
    __shared__ int s[256];
    int i = blockIdx.x * 256 + threadIdx.x;
    int v = (i < n) ? deg[i] : 0;
    s[threadIdx.x] = v;
    __syncthreads();
    for (int off = 1; off < 256; off <<= 1) {
        int t = (threadIdx.x >= off) ? s[threadIdx.x - off] : 0;
        __syncthreads();
        s[threadIdx.x] += t;
        __syncthreads();
    }
    if (i < n) excl[i] = s[threadIdx.x] - v;
    if (threadIdx.x == 255) psum[blockIdx.x] = s[255];
}

__global__ void scan_partials_kernel(int* __restrict__ psum, int nb) {
    __shared__ int s[512];
    int v = (threadIdx.x < nb) ? psum[threadIdx.x] : 0;
    s[threadIdx.x] = v;
    __syncthreads();
    for (int off = 1; off < 512; off <<= 1) {
        int t = (threadIdx.x >= off) ? s[threadIdx.x - off] : 0;
        __syncthreads();
        s[threadIdx.x] += t;
        __syncthreads();
    }
    if (threadIdx.x < nb) psum[threadIdx.x] = s[threadIdx.x] - v;   // exclusive
}

__global__ void scan_add_kernel(int* __restrict__ excl, const int* __restrict__ psum, int n) {
    int i = blockIdx.x * 256 + threadIdx.x;
    if (i < n) excl[i] += psum[blockIdx.x];
}

__global__ void scatter_kernel(const int* __restrict__ src, const int* __restrict__ dst,
                               const int* __restrict__ rowstart, int* __restrict__ cursor,
                               int* __restrict__ esrc, int E, int ET) {
    int e = blockIdx.x * blockDim.x + threadIdx.x;
    if (e >= ET) return;
    int s = (e < E) ? src[e] : (e - E);
    int d = (e < E) ? dst[e] : (e - E);
    int slot = rowstart[d] + atomicAdd(&cursor[d], 1);
    esrc[slot] = s;
}

// ---------- per-dst-segment softmax (sequential, no atomics) ----------
__global__ void softmax_kernel(const int* __restrict__ rowstart, const int* __restrict__ deg,
                               const int* __restrict__ esrc,
                               const float* __restrict__ asrc, const float* __restrict__ adst,
                               float* __restrict__ alpha, float* __restrict__ sinv) {
    int n = blockIdx.x * blockDim.x + threadIdx.x;
    if (n >= NNODES) return;
    int row = rowstart[n], dg = deg[n];
    float ad0 = adst[2 * n], ad1 = adst[2 * n + 1];
    float m0 = -1e30f, m1 = -1e30f;
    for (int i = 0; i < dg; ++i) {
        int s = esrc[row + i];
        float l0 = asrc[2 * s] + ad0;
        float l1 = asrc[2 * s + 1] + ad1;
        l0 = (l0 > 0.f) ? l0 : NEG_SLOPE * l0;
        l1 = (l1 > 0.f) ? l1 : NEG_SLOPE * l1;
        alpha[2 * (size_t)(row + i)] = l0;
        alpha[2 * (size_t)(row + i) + 1] = l1;
        m0 = fmaxf(m0, l0);
        m1 = fmaxf(m1, l1);
    }
    float s0 = 0.f, s1 = 0.f;
    for (int i = 0; i < dg; ++i) {
        float e0 = expf(alpha[2 * (size_t)(row + i)] - m0);
        float e1 = expf(alpha[2 * (size_t)(row + i) + 1] - m1);
        alpha[2 * (size_t)(row + i)] = e0;
        alpha[2 * (size_t)(row + i) + 1] = e1;
        s0 += e0;
        s1 += e1;
    }
    sinv[2 * n] = 1.f / (s0 + 1e-16f);
    sinv[2 * n + 1] = 1.f / (s1 + 1e-16f);
}

// ---------- gather-aggregate: one block (128 thr) per dst node ----------
template <bool TO_G>
__global__ void aggregate_kernel(const int* __restrict__ rowstart, const int* __restrict__ deg,
                                 const int* __restrict__ esrc,
                                 const float* __restrict__ alpha, const float* __restrict__ sinv,
                                 const float* __restrict__ xw, const float* __restrict__ bias,
                                 float* __restrict__ out, const int* __restrict__ batch,
                                 float* __restrict__ g) {
    int n = blockIdx.x;
    int j = threadIdx.x;
    int h = j >> 6;
    int row = rowstart[n], dg = deg[n];
    float acc = 0.f;
    for (int i = 0; i < dg; ++i) {
        int s = esrc[row + i];
        float a = alpha[2 * (size_t)(row + i) + h];
        acc += a * xw[(size_t)s * 128 + j];
    }
    acc *= sinv[2 * n + h];
    __shared__ float sh[128];
    sh[j] = acc;
    __syncthreads();
    if (j < 64) {
        float v = 0.5f * (sh[j] + sh[j + 64]) + bias[j];
        v = (v > 0.f) ? v : 0.f;
        if (TO_G) atomicAdd(&g[batch[n] * 64 + j], v);
        else out[(size_t)n * 64 + j] = v;
    }
}

// ---------- final FC + log_softmax ----------
__global__ void final_fc_kernel(const float* __restrict__ g, const float* __restrict__ Wfc,
                                const float* __restrict__ bfc, float* __restrict__ out) {
    int gi = threadIdx.x;
    if (gi >= NGRAPHS) return;
    float logit[10];
    #pragma unroll
    for (int o = 0; o < 10; ++o) logit[o] = bfc[o];
    for (int c = 0; c < 64; ++c) {
        float gv = g[gi * 64 + c];
        #pragma unroll
        for (int o = 0; o < 10; ++o) logit[o] += gv * Wfc[c * 10 + o];
    }
    float mx = logit[0];
    #pragma unroll
    for (int o = 1; o < 10; ++o) mx = fmaxf(mx, logit[o]);
    float se = 0.f;
    #pragma unroll
    for (int o = 0; o < 10; ++o) se += expf(logit[o] - mx);
    float lse = mx + logf(se);
    #pragma unroll
    for (int o = 0; o < 10; ++o) out[gi * 10 + o] = logit[o] - lse;
}

extern "C" void kernel_launch(void* const* d_in, const int* in_sizes, int n_in,
                              void* d_out, int out_size, void* d_ws, size_t ws_size,
                              hipStream_t stream) {
    const float* x        = (const float*)d_in[0];
    const float* W1       = (const float*)d_in[1];
    const float* att_src1 = (const float*)d_in[2];
    const float* att_dst1 = (const float*)d_in[3];
    const float* b1       = (const float*)d_in[4];
    const float* W2       = (const float*)d_in[5];
    const float* att_src2 = (const float*)d_in[6];
    const float* att_dst2 = (const float*)d_in[7];
    const float* b2       = (const float*)d_in[8];
    const float* Wfc      = (const float*)d_in[9];
    const float* bfc      = (const float*)d_in[10];
    const int*   eidx     = (const int*)d_in[11];
    const int*   batch    = (const int*)d_in[12];
    float* out = (float*)d_out;

    const int E  = in_sizes[11] / 2;
    const int ET = E + NNODES;
    const int* srcp = eidx;
    const int* dstp = eidx + E;

    // workspace layout
    char* w = (char*)d_ws;
    float* xw   = (float*)w;                 w += (size_t)NNODES * 128 * 4;
    float* asrc = (float*)w;                 w += (size_t)NNODES * 2 * 4;
    float* adst = (float*)w;                 w += (size_t)NNODES * 2 * 4;
    float* alpha = (float*)w;                w += (size_t)ET * 2 * 4;
    float* sinv = (float*)w;                 w += (size_t)NNODES * 2 * 4;
    float* h1   = (float*)w;                 w += (size_t)NNODES * 64 * 4;
    float* g    = (float*)w;                 w += (size_t)NGRAPHS * 64 * 4;
    int* deg     = (int*)w;                  w += (size_t)NNODES * 4;
    int* rowstart= (int*)w;                  w += (size_t)NNODES * 4;
    int* cursor  = (int*)w;                  w += (size_t)NNODES * 4;
    int* psum    = (int*)w;                  w += 512 * 4;
    int* esrc    = (int*)w;                  w += (size_t)ET * 4;

    const int BLK = 256;
    const int NB  = (NNODES + 255) / 256;    // 391 <= 512
    int grid_et   = (ET + BLK - 1) / BLK;
    int grid_n2   = (NNODES * 2 + BLK - 1) / BLK;
    int grid_n    = (NNODES + BLK - 1) / BLK;

    // ---- CSR build (once, shared by both layers) ----
    hipMemsetAsync(deg, 0, (size_t)NNODES * 4, stream);
    hipMemsetAsync(cursor, 0, (size_t)NNODES * 4, stream);
    hipMemsetAsync(g, 0, (size_t)NGRAPHS * 64 * 4, stream);
    hist_kernel<<<grid_et, BLK, 0, stream>>>(dstp, deg, E, ET);
    scan_block_kernel<<<NB, 256, 0, stream>>>(deg, rowstart, psum, NNODES);
    scan_partials_kernel<<<1, 512, 0, stream>>>(psum, NB);
    scan_add_kernel<<<NB, 256, 0, stream>>>(rowstart, psum, NNODES);
    scatter_kernel<<<grid_et, BLK, 0, stream>>>(srcp, dstp, rowstart, cursor, esrc, E, ET);

    dim3 gemm_grid1(128 / BN, (NNODES + BM - 1) / BM);

    // ---- layer 1 ----
    gemm_kernel<<<gemm_grid1, BLK, 0, stream>>>(x, W1, xw, NNODES, 128, 128);
    att_node_kernel<<<grid_n2, BLK, 0, stream>>>(xw, att_src1, att_dst1, asrc, adst);
    softmax_kernel<<<grid_n, BLK, 0, stream>>>(rowstart, deg, esrc, asrc, adst, alpha, sinv);
    aggregate_kernel<false><<<NNODES, 128, 0, stream>>>(rowstart, deg, esrc, alpha, sinv,
                                                        xw, b1, h1, nullptr, nullptr);

    // ---- layer 2 ----
    gemm_kernel<<<gemm_grid1, BLK, 0, stream>>>(h1, W2, xw, NNODES, 64, 128);
    att_node_kernel<<<grid_n2, BLK, 0, stream>>>(xw, att_src2, att_dst2, asrc, adst);
    softmax_kernel<<<grid_n, BLK, 0, stream>>>(rowstart, deg, esrc, asrc, adst, alpha, sinv);
    aggregate_kernel<true><<<NNODES, 128, 0, stream>>>(rowstart, deg, esrc, alpha, sinv,
                                                       xw, b2, nullptr, batch, g);

    // ---- final FC + log_softmax ----
    final_fc_kernel<<<1, 128, 0, stream>>>(g, Wfc, bfc, out);
}

// Round 3
// 858.094 us; speedup vs baseline: 2.7492x; 1.0337x over previous
//
#include <hip/hip_runtime.h>
#include <cstdint>
#include <cstddef>

#define NNODES 100000
#define NGRAPHS 128
#define NEG_SLOPE 0.2f

// ---------- GEMM: C[M,N] = A[M,K] @ B[K,N], row-major ----------
#define BM 64
#define BN 64
#define BK 16
__global__ void gemm_kernel(const float* __restrict__ A, const float* __restrict__ B,
                            float* __restrict__ C, int M, int K, int N) {
    __shared__ float As[BK][BM + 1];
    __shared__ float Bs[BK][BN + 1];
    int tid = threadIdx.x;
    int tx = tid & 15;   // N dir
    int ty = tid >> 4;   // M dir
    int row0 = blockIdx.y * BM;
    int col0 = blockIdx.x * BN;

    float acc[4][4] = {};

    for (int k0 = 0; k0 < K; k0 += BK) {
        {
            int r  = tid >> 2;
            int kb = (tid & 3) * 4;
            int grow = row0 + r;
            #pragma unroll
            for (int u = 0; u < 4; ++u) {
                float v = 0.f;
                if (grow < M) v = A[(size_t)grow * K + k0 + kb + u];
                As[kb + u][r] = v;
            }
        }
        {
            int kk = tid >> 4;
            int cb = (tid & 15) * 4;
            #pragma unroll
            for (int u = 0; u < 4; ++u) {
                Bs[kk][cb + u] = B[(size_t)(k0 + kk) * N + col0 + cb + u];
            }
        }
        __syncthreads();
        #pragma unroll
        for (int kk = 0; kk < BK; ++kk) {
            float a[4], b[4];
            #pragma unroll
            for (int i = 0; i < 4; ++i) a[i] = As[kk][ty * 4 + i];
            #pragma unroll
            for (int j = 0; j < 4; ++j) b[j] = Bs[kk][tx * 4 + j];
            #pragma unroll
            for (int i = 0; i < 4; ++i)
                #pragma unroll
                for (int j = 0; j < 4; ++j)
                    acc[i][j] += a[i] * b[j];
        }
        __syncthreads();
    }

    #pragma unroll
    for (int i = 0; i < 4; ++i) {
        int row = row0 + ty * 4 + i;
        if (row >= M) continue;
        #pragma unroll
        for (int j = 0; j < 4; ++j) {
            int col = col0 + tx * 4 + j;
            if (col < N) C[(size_t)row * N + col] = acc[i][j];
        }
    }
}

// ---------- bf16 pack: xwp[n*64+c] = {bf16 xw[n,c], bf16 xw[n,c+64]} ----------
static __device__ __forceinline__ unsigned int bf16_rne(float f) {
    unsigned int x = __float_as_uint(f);
    return (x + 0x7fffu + ((x >> 16) & 1u)) >> 16;
}

__global__ void pack_kernel(const float* __restrict__ xw, unsigned int* __restrict__ xwp) {
    int idx = blockIdx.x * blockDim.x + threadIdx.x;
    if (idx >= NNODES * 64) return;
    int n = idx >> 6, c = idx & 63;
    float lo = xw[(size_t)n * 128 + c];
    float hi = xw[(size_t)n * 128 + 64 + c];
    xwp[idx] = bf16_rne(lo) | (bf16_rne(hi) << 16);
}

// ---------- per-node attention coefficients ----------
__global__ void att_node_kernel(const float* __restrict__ xw,
                                const float* __restrict__ att_src,
                                const float* __restrict__ att_dst,
                                float* __restrict__ asrc, float* __restrict__ adst) {
    int idx = blockIdx.x * blockDim.x + threadIdx.x;
    if (idx >= NNODES * 2) return;
    int n = idx >> 1, h = idx & 1;
    const float* row = xw + (size_t)n * 128 + h * 64;
    const float* as = att_src + h * 64;
    const float* ad = att_dst + h * 64;
    float s1 = 0.f, s2 = 0.f;
    for (int c = 0; c < 64; ++c) {
        float v = row[c];
        s1 += v * as[c];
        s2 += v * ad[c];
    }
    asrc[idx] = s1;
    adst[idx] = s2;
}

// ---------- CSR build ----------
__global__ void hist_kernel(const int* __restrict__ dst, int* __restrict__ deg, int E, int ET) {
    int e = blockIdx.x * blockDim.x + threadIdx.x;
    if (e >= ET) return;
    int d = (e < E) ? dst[e] : (e - E);
    atomicAdd(&deg[d], 1);
}

__global__ void scan_block_kernel(const int* __restrict__ deg, int* __restrict__ excl,
                                  int* __restrict__ psum, int n) {
    __shared__ int s[256];
    int i = blockIdx.x * 256 + threadIdx.x;
    int v = (i < n) ? deg[i] : 0;
    s[threadIdx.x] = v;
    __syncthreads();
    for (int off = 1; off < 256; off <<= 1) {
        int t = (threadIdx.x >= off) ? s[threadIdx.x - off] : 0;
        __syncthreads();
        s[threadIdx.x] += t;
        __syncthreads();
    }
    if (i < n) excl[i] = s[threadIdx.x] - v;
    if (threadIdx.x == 255) psum[blockIdx.x] = s[255];
}

__global__ void scan_partials_kernel(int* __restrict__ psum, int nb) {
    __shared__ int s[512];
    int v = (threadIdx.x < nb) ? psum[threadIdx.x] : 0;
    s[threadIdx.x] = v;
    __syncthreads();
    for (int off = 1; off < 512; off <<= 1) {
        int t = (threadIdx.x >= off) ? s[threadIdx.x - off] : 0;
        __syncthreads();
        s[threadIdx.x] += t;
        __syncthreads();
    }
    if (threadIdx.x < nb) psum[threadIdx.x] = s[threadIdx.x] - v;   // exclusive
}

__global__ void scan_add_kernel(int* __restrict__ excl, const int* __restrict__ psum, int n) {
    int i = blockIdx.x * 256 + threadIdx.x;
    if (i < n) excl[i] += psum[blockIdx.x];
}

__global__ void scatter_kernel(const int* __restrict__ src, const int* __restrict__ dst,
                               const int* __restrict__ rowstart, int* __restrict__ cursor,
                               int* __restrict__ esrc, int E, int ET) {
    int e = blockIdx.x * blockDim.x + threadIdx.x;
    if (e >= ET) return;
    int s = (e < E) ? src[e] : (e - E);
    int d = (e < E) ? dst[e] : (e - E);
    int slot = rowstart[d] + atomicAdd(&cursor[d], 1);
    esrc[slot] = s;
}

// ---------- per-dst-segment softmax (sequential, no atomics) ----------
__global__ void softmax_kernel(const int* __restrict__ rowstart, const int* __restrict__ deg,
                               const int* __restrict__ esrc,
                               const float* __restrict__ asrc, const float* __restrict__ adst,
                               float* __restrict__ alpha, float* __restrict__ sinv) {
    int n = blockIdx.x * blockDim.x + threadIdx.x;
    if (n >= NNODES) return;
    int row = rowstart[n], dg = deg[n];
    float ad0 = adst[2 * n], ad1 = adst[2 * n + 1];
    float m0 = -1e30f, m1 = -1e30f;
    for (int i = 0; i < dg; ++i) {
        int s = esrc[row + i];
        float l0 = asrc[2 * s] + ad0;
        float l1 = asrc[2 * s + 1] + ad1;
        l0 = (l0 > 0.f) ? l0 : NEG_SLOPE * l0;
        l1 = (l1 > 0.f) ? l1 : NEG_SLOPE * l1;
        alpha[2 * (size_t)(row + i)] = l0;
        alpha[2 * (size_t)(row + i) + 1] = l1;
        m0 = fmaxf(m0, l0);
        m1 = fmaxf(m1, l1);
    }
    float s0 = 0.f, s1 = 0.f;
    for (int i = 0; i < dg; ++i) {
        float e0 = expf(alpha[2 * (size_t)(row + i)] - m0);
        float e1 = expf(alpha[2 * (size_t)(row + i) + 1] - m1);
        alpha[2 * (size_t)(row + i)] = e0;
        alpha[2 * (size_t)(row + i) + 1] = e1;
        s0 += e0;
        s1 += e1;
    }
    sinv[2 * n] = 1.f / (s0 + 1e-16f);
    sinv[2 * n + 1] = 1.f / (s1 + 1e-16f);
}

// ---------- gather-aggregate: one WAVE per dst node, bf16-packed gather ----------
template <bool TO_G>
__global__ void aggregate_kernel(const int* __restrict__ rowstart, const int* __restrict__ deg,
                                 const int* __restrict__ esrc,
                                 const float* __restrict__ alpha, const float* __restrict__ sinv,
                                 const unsigned int* __restrict__ xwp, const float* __restrict__ bias,
                                 float* __restrict__ out, const int* __restrict__ batch,
                                 float* __restrict__ g) {
    int wid  = threadIdx.x >> 6;
    int lane = threadIdx.x & 63;
    int n = blockIdx.x * 4 + wid;
    if (n >= NNODES) return;
    int row = rowstart[n], dg = deg[n];
    float acc0 = 0.f, acc1 = 0.f;
    for (int i = 0; i < dg; ++i) {
        int s = esrc[row + i];
        float2 a = ((const float2*)alpha)[row + i];
        unsigned int u = xwp[(size_t)s * 64 + lane];
        float lo = __uint_as_float(u << 16);
        float hi = __uint_as_float(u & 0xffff0000u);
        acc0 += a.x * lo;
        acc1 += a.y * hi;
    }
    float v = 0.5f * (acc0 * sinv[2 * n] + acc1 * sinv[2 * n + 1]) + bias[lane];
    v = (v > 0.f) ? v : 0.f;
    if (TO_G) atomicAdd(&g[batch[n] * 64 + lane], v);
    else out[(size_t)n * 64 + lane] = v;
}

// ---------- final FC + log_softmax ----------
__global__ void final_fc_kernel(const float* __restrict__ g, const float* __restrict__ Wfc,
                                const float* __restrict__ bfc, float* __restrict__ out) {
    int gi = threadIdx.x;
    if (gi >= NGRAPHS) return;
    float logit[10];
    #pragma unroll
    for (int o = 0; o < 10; ++o) logit[o] = bfc[o];
    for (int c = 0; c < 64; ++c) {
        float gv = g[gi * 64 + c];
        #pragma unroll
        for (int o = 0; o < 10; ++o) logit[o] += gv * Wfc[c * 10 + o];
    }
    float mx = logit[0];
    #pragma unroll
    for (int o = 1; o < 10; ++o) mx = fmaxf(mx, logit[o]);
    float se = 0.f;
    #pragma unroll
    for (int o = 0; o < 10; ++o) se += expf(logit[o] - mx);
    float lse = mx + logf(se);
    #pragma unroll
    for (int o = 0; o < 10; ++o) out[gi * 10 + o] = logit[o] - lse;
}

extern "C" void kernel_launch(void* const* d_in, const int* in_sizes, int n_in,
                              void* d_out, int out_size, void* d_ws, size_t ws_size,
                              hipStream_t stream) {
    const float* x        = (const float*)d_in[0];
    const float* W1       = (const float*)d_in[1];
    const float* att_src1 = (const float*)d_in[2];
    const float* att_dst1 = (const float*)d_in[3];
    const float* b1       = (const float*)d_in[4];
    const float* W2       = (const float*)d_in[5];
    const float* att_src2 = (const float*)d_in[6];
    const float* att_dst2 = (const float*)d_in[7];
    const float* b2       = (const float*)d_in[8];
    const float* Wfc      = (const float*)d_in[9];
    const float* bfc      = (const float*)d_in[10];
    const int*   eidx     = (const int*)d_in[11];
    const int*   batch    = (const int*)d_in[12];
    float* out = (float*)d_out;

    const int E  = in_sizes[11] / 2;
    const int ET = E + NNODES;
    const int* srcp = eidx;
    const int* dstp = eidx + E;

    // workspace layout
    char* w = (char*)d_ws;
    float* xw   = (float*)w;                 w += (size_t)NNODES * 128 * 4;
    unsigned int* xwp = (unsigned int*)w;    w += (size_t)NNODES * 64 * 4;
    float* asrc = (float*)w;                 w += (size_t)NNODES * 2 * 4;
    float* adst = (float*)w;                 w += (size_t)NNODES * 2 * 4;
    float* alpha = (float*)w;                w += (size_t)ET * 2 * 4;
    float* sinv = (float*)w;                 w += (size_t)NNODES * 2 * 4;
    float* h1   = (float*)w;                 w += (size_t)NNODES * 64 * 4;
    float* g    = (float*)w;                 w += (size_t)NGRAPHS * 64 * 4;
    int* deg     = (int*)w;                  w += (size_t)NNODES * 4;
    int* rowstart= (int*)w;                  w += (size_t)NNODES * 4;
    int* cursor  = (int*)w;                  w += (size_t)NNODES * 4;
    int* psum    = (int*)w;                  w += 512 * 4;
    int* esrc    = (int*)w;                  w += (size_t)ET * 4;

    const int BLK = 256;
    const int NB  = (NNODES + 255) / 256;    // 391 <= 512
    int grid_et   = (ET + BLK - 1) / BLK;
    int grid_n2   = (NNODES * 2 + BLK - 1) / BLK;
    int grid_n    = (NNODES + BLK - 1) / BLK;
    int grid_n64  = (NNODES * 64 + BLK - 1) / BLK;
    int grid_agg  = (NNODES + 3) / 4;

    // ---- CSR build (once, shared by both layers) ----
    hipMemsetAsync(deg, 0, (size_t)NNODES * 4, stream);
    hipMemsetAsync(cursor, 0, (size_t)NNODES * 4, stream);
    hipMemsetAsync(g, 0, (size_t)NGRAPHS * 64 * 4, stream);
    hist_kernel<<<grid_et, BLK, 0, stream>>>(dstp, deg, E, ET);
    scan_block_kernel<<<NB, 256, 0, stream>>>(deg, rowstart, psum, NNODES);
    scan_partials_kernel<<<1, 512, 0, stream>>>(psum, NB);
    scan_add_kernel<<<NB, 256, 0, stream>>>(rowstart, psum, NNODES);
    scatter_kernel<<<grid_et, BLK, 0, stream>>>(srcp, dstp, rowstart, cursor, esrc, E, ET);

    dim3 gemm_grid1(128 / BN, (NNODES + BM - 1) / BM);

    // ---- layer 1 ----
    gemm_kernel<<<gemm_grid1, BLK, 0, stream>>>(x, W1, xw, NNODES, 128, 128);
    pack_kernel<<<grid_n64, BLK, 0, stream>>>(xw, xwp);
    att_node_kernel<<<grid_n2, BLK, 0, stream>>>(xw, att_src1, att_dst1, asrc, adst);
    softmax_kernel<<<grid_n, BLK, 0, stream>>>(rowstart, deg, esrc, asrc, adst, alpha, sinv);
    aggregate_kernel<false><<<grid_agg, BLK, 0, stream>>>(rowstart, deg, esrc, alpha, sinv,
                                                          xwp, b1, h1, nullptr, nullptr);

    // ---- layer 2 ----
    gemm_kernel<<<gemm_grid1, BLK, 0, stream>>>(h1, W2, xw, NNODES, 64, 128);
    pack_kernel<<<grid_n64, BLK, 0, stream>>>(xw, xwp);
    att_node_kernel<<<grid_n2, BLK, 0, stream>>>(xw, att_src2, att_dst2, asrc, adst);
    softmax_kernel<<<grid_n, BLK, 0, stream>>>(rowstart, deg, esrc, asrc, adst, alpha, sinv);
    aggregate_kernel<true><<<grid_agg, BLK, 0, stream>>>(rowstart, deg, esrc, alpha, sinv,
                                                         xwp, b2, nullptr, batch, g);

    // ---- final FC + log_softmax ----
    final_fc_kernel<<<1, 128, 0, stream>>>(g, Wfc, bfc, out);
}

// Round 4
// 623.689 us; speedup vs baseline: 3.7824x; 1.3758x over previous
//
#include <hip/hip_runtime.h>
#include <cstdint>
#include <cstddef>

#define NNODES 100000
#define NGRAPHS 128
#define NEG_SLOPE 0.2f

static __device__ __forceinline__ unsigned int bf16_rne(float f) {
    unsigned int x = __float_as_uint(f);
    return (x + 0x7fffu + ((x >> 16) & 1u)) >> 16;
}

// ---------- fused GEMM + bf16 pack + attention coefficients ----------
// C = A[M,K] @ B[K,128]; blockIdx.x = head h (64-col half); blockIdx.y = row tile.
// Outputs: xwp16[row*128 + c*2 + h] = bf16(C[row, h*64+c])   (so uint xwp[row*64+c] = {h0,h1})
//          asrc[row*2+h], adst[row*2+h] = dot(C[row, h*64:...], att_src/att_dst[h])
#define BM 64
#define BK 16
__global__ void gemm_fused_kernel(const float* __restrict__ A, const float* __restrict__ B,
                                  unsigned short* __restrict__ xwp16,
                                  const float* __restrict__ att_src, const float* __restrict__ att_dst,
                                  float* __restrict__ asrc, float* __restrict__ adst,
                                  int M, int K) {
    __shared__ float As[BK][BM + 1];
    __shared__ float Bs[BK][64 + 1];
    int tid = threadIdx.x;
    int tx = tid & 15;   // col dir (4 cols each)
    int ty = tid >> 4;   // row dir (4 rows each)
    int row0 = blockIdx.y * BM;
    int h = blockIdx.x;
    int col0 = h * 64;

    float acc[4][4] = {};

    for (int k0 = 0; k0 < K; k0 += BK) {
        {
            int r  = tid >> 2;
            int kb = (tid & 3) * 4;
            int grow = row0 + r;
            #pragma unroll
            for (int u = 0; u < 4; ++u) {
                float v = 0.f;
                if (grow < M) v = A[(size_t)grow * K + k0 + kb + u];
                As[kb + u][r] = v;
            }
        }
        {
            int kk = tid >> 4;
            int cb = (tid & 15) * 4;
            #pragma unroll
            for (int u = 0; u < 4; ++u) {
                Bs[kk][cb + u] = B[(size_t)(k0 + kk) * 128 + col0 + cb + u];
            }
        }
        __syncthreads();
        #pragma unroll
        for (int kk = 0; kk < BK; ++kk) {
            float a[4], b[4];
            #pragma unroll
            for (int i = 0; i < 4; ++i) a[i] = As[kk][ty * 4 + i];
            #pragma unroll
            for (int j = 0; j < 4; ++j) b[j] = Bs[kk][tx * 4 + j];
            #pragma unroll
            for (int i = 0; i < 4; ++i)
                #pragma unroll
                for (int j = 0; j < 4; ++j)
                    acc[i][j] += a[i] * b[j];
        }
        __syncthreads();
    }

    // attention partial dot-products, reduce over the 16 tx lanes
    float ps[4] = {}, pd[4] = {};
    #pragma unroll
    for (int j = 0; j < 4; ++j) {
        float ws = att_src[h * 64 + tx * 4 + j];
        float wd = att_dst[h * 64 + tx * 4 + j];
        #pragma unroll
        for (int i = 0; i < 4; ++i) { ps[i] += acc[i][j] * ws; pd[i] += acc[i][j] * wd; }
    }
    #pragma unroll
    for (int off = 1; off < 16; off <<= 1) {
        #pragma unroll
        for (int i = 0; i < 4; ++i) {
            ps[i] += __shfl_xor(ps[i], off);
            pd[i] += __shfl_xor(pd[i], off);
        }
    }
    if (tx == 0) {
        #pragma unroll
        for (int i = 0; i < 4; ++i) {
            int row = row0 + ty * 4 + i;
            if (row < M) { asrc[row * 2 + h] = ps[i]; adst[row * 2 + h] = pd[i]; }
        }
    }

    // bf16 packed store (interleaved ushort: [row][c][h])
    #pragma unroll
    for (int i = 0; i < 4; ++i) {
        int row = row0 + ty * 4 + i;
        if (row >= M) continue;
        #pragma unroll
        for (int j = 0; j < 4; ++j) {
            int c = tx * 4 + j;
            xwp16[(size_t)row * 128 + c * 2 + h] = (unsigned short)bf16_rne(acc[i][j]);
        }
    }
}

// ---------- CSR build ----------
__global__ void hist_kernel(const int* __restrict__ dst, int* __restrict__ deg, int E, int ET) {
    int e = blockIdx.x * blockDim.x + threadIdx.x;
    if (e >= ET) return;
    int d = (e < E) ? dst[e] : (e - E);
    atomicAdd(&deg[d], 1);
}

__global__ void scan_block_kernel(const int* __restrict__ deg, int* __restrict__ excl,
                                  int* __restrict__ psum, int n) {
    __shared__ int s[256];
    int i = blockIdx.x * 256 + threadIdx.x;
    int v = (i < n) ? deg[i] : 0;
    s[threadIdx.x] = v;
    __syncthreads();
    for (int off = 1; off < 256; off <<= 1) {
        int t = (threadIdx.x >= off) ? s[threadIdx.x - off] : 0;
        __syncthreads();
        s[threadIdx.x] += t;
        __syncthreads();
    }
    if (i < n) excl[i] = s[threadIdx.x] - v;
    if (threadIdx.x == 255) psum[blockIdx.x] = s[255];
}

__global__ void scan_partials_kernel(int* __restrict__ psum, int nb) {
    __shared__ int s[512];
    int v = (threadIdx.x < nb) ? psum[threadIdx.x] : 0;
    s[threadIdx.x] = v;
    __syncthreads();
    for (int off = 1; off < 512; off <<= 1) {
        int t = (threadIdx.x >= off) ? s[threadIdx.x - off] : 0;
        __syncthreads();
        s[threadIdx.x] += t;
        __syncthreads();
    }
    if (threadIdx.x < nb) psum[threadIdx.x] = s[threadIdx.x] - v;   // exclusive
}

__global__ void scan_add_kernel(int* __restrict__ excl, const int* __restrict__ psum, int n) {
    int i = blockIdx.x * 256 + threadIdx.x;
    if (i < n) excl[i] += psum[blockIdx.x];
}

__global__ void scatter_kernel(const int* __restrict__ src, const int* __restrict__ dst,
                               const int* __restrict__ rowstart, int* __restrict__ cursor,
                               int* __restrict__ esrc, int E, int ET) {
    int e = blockIdx.x * blockDim.x + threadIdx.x;
    if (e >= ET) return;
    int s = (e < E) ? src[e] : (e - E);
    int d = (e < E) ? dst[e] : (e - E);
    int slot = rowstart[d] + atomicAdd(&cursor[d], 1);
    esrc[slot] = s;
}

// ---------- per-dst-segment softmax (sequential, no atomics) ----------
__global__ void softmax_kernel(const int* __restrict__ rowstart, const int* __restrict__ deg,
                               const int* __restrict__ esrc,
                               const float* __restrict__ asrc, const float* __restrict__ adst,
                               float* __restrict__ alpha, float* __restrict__ sinv) {
    int n = blockIdx.x * blockDim.x + threadIdx.x;
    if (n >= NNODES) return;
    int row = rowstart[n], dg = deg[n];
    float ad0 = adst[2 * n], ad1 = adst[2 * n + 1];
    float m0 = -1e30f, m1 = -1e30f;
    for (int i = 0; i < dg; ++i) {
        int s = esrc[row + i];
        float l0 = asrc[2 * s] + ad0;
        float l1 = asrc[2 * s + 1] + ad1;
        l0 = (l0 > 0.f) ? l0 : NEG_SLOPE * l0;
        l1 = (l1 > 0.f) ? l1 : NEG_SLOPE * l1;
        alpha[2 * (size_t)(row + i)] = l0;
        alpha[2 * (size_t)(row + i) + 1] = l1;
        m0 = fmaxf(m0, l0);
        m1 = fmaxf(m1, l1);
    }
    float s0 = 0.f, s1 = 0.f;
    for (int i = 0; i < dg; ++i) {
        float e0 = expf(alpha[2 * (size_t)(row + i)] - m0);
        float e1 = expf(alpha[2 * (size_t)(row + i) + 1] - m1);
        alpha[2 * (size_t)(row + i)] = e0;
        alpha[2 * (size_t)(row + i) + 1] = e1;
        s0 += e0;
        s1 += e1;
    }
    sinv[2 * n] = 1.f / (s0 + 1e-16f);
    sinv[2 * n + 1] = 1.f / (s1 + 1e-16f);
}

// ---------- gather-aggregate: one WAVE per dst node, 8-deep MLP unroll ----------
template <bool TO_G>
__global__ void aggregate_kernel(const int* __restrict__ rowstart, const int* __restrict__ deg,
                                 const int* __restrict__ esrc,
                                 const float2* __restrict__ alpha, const float* __restrict__ sinv,
                                 const unsigned int* __restrict__ xwp, const float* __restrict__ bias,
                                 float* __restrict__ out, const int* __restrict__ batch,
                                 float* __restrict__ g) {
    int wid  = threadIdx.x >> 6;
    int lane = threadIdx.x & 63;
    int n = blockIdx.x * 4 + wid;
    if (n >= NNODES) return;
    int row = rowstart[n], dg = deg[n];
    float acc0 = 0.f, acc1 = 0.f;
    int i = 0;

#define LOADG(k) int s##k = esrc[row + i + k]; \
                 float2 a##k = alpha[row + i + k]; \
                 unsigned int u##k = xwp[(size_t)s##k * 64 + lane]
#define FMAG(k)  acc0 += a##k.x * __uint_as_float(u##k << 16); \
                 acc1 += a##k.y * __uint_as_float(u##k & 0xffff0000u)

    for (; i + 8 <= dg; i += 8) {
        LOADG(0); LOADG(1); LOADG(2); LOADG(3);
        LOADG(4); LOADG(5); LOADG(6); LOADG(7);
        FMAG(0); FMAG(1); FMAG(2); FMAG(3);
        FMAG(4); FMAG(5); FMAG(6); FMAG(7);
    }
    for (; i + 2 <= dg; i += 2) {
        LOADG(0); LOADG(1);
        FMAG(0); FMAG(1);
    }
    if (i < dg) {
        LOADG(0);
        FMAG(0);
    }
#undef LOADG
#undef FMAG

    float v = 0.5f * (acc0 * sinv[2 * n] + acc1 * sinv[2 * n + 1]) + bias[lane];
    v = (v > 0.f) ? v : 0.f;
    if (TO_G) atomicAdd(&g[batch[n] * 64 + lane], v);
    else out[(size_t)n * 64 + lane] = v;
}

// ---------- final FC + log_softmax ----------
__global__ void final_fc_kernel(const float* __restrict__ g, const float* __restrict__ Wfc,
                                const float* __restrict__ bfc, float* __restrict__ out) {
    int gi = threadIdx.x;
    if (gi >= NGRAPHS) return;
    float logit[10];
    #pragma unroll
    for (int o = 0; o < 10; ++o) logit[o] = bfc[o];
    for (int c = 0; c < 64; ++c) {
        float gv = g[gi * 64 + c];
        #pragma unroll
        for (int o = 0; o < 10; ++o) logit[o] += gv * Wfc[c * 10 + o];
    }
    float mx = logit[0];
    #pragma unroll
    for (int o = 1; o < 10; ++o) mx = fmaxf(mx, logit[o]);
    float se = 0.f;
    #pragma unroll
    for (int o = 0; o < 10; ++o) se += expf(logit[o] - mx);
    float lse = mx + logf(se);
    #pragma unroll
    for (int o = 0; o < 10; ++o) out[gi * 10 + o] = logit[o] - lse;
}

extern "C" void kernel_launch(void* const* d_in, const int* in_sizes, int n_in,
                              void* d_out, int out_size, void* d_ws, size_t ws_size,
                              hipStream_t stream) {
    const float* x        = (const float*)d_in[0];
    const float* W1       = (const float*)d_in[1];
    const float* att_src1 = (const float*)d_in[2];
    const float* att_dst1 = (const float*)d_in[3];
    const float* b1       = (const float*)d_in[4];
    const float* W2       = (const float*)d_in[5];
    const float* att_src2 = (const float*)d_in[6];
    const float* att_dst2 = (const float*)d_in[7];
    const float* b2       = (const float*)d_in[8];
    const float* Wfc      = (const float*)d_in[9];
    const float* bfc      = (const float*)d_in[10];
    const int*   eidx     = (const int*)d_in[11];
    const int*   batch    = (const int*)d_in[12];
    float* out = (float*)d_out;

    const int E  = in_sizes[11] / 2;
    const int ET = E + NNODES;
    const int* srcp = eidx;
    const int* dstp = eidx + E;

    // workspace layout
    char* w = (char*)d_ws;
    unsigned int* xwp = (unsigned int*)w;    w += (size_t)NNODES * 64 * 4;
    float* asrc = (float*)w;                 w += (size_t)NNODES * 2 * 4;
    float* adst = (float*)w;                 w += (size_t)NNODES * 2 * 4;
    float* alpha = (float*)w;                w += (size_t)ET * 2 * 4;
    float* sinv = (float*)w;                 w += (size_t)NNODES * 2 * 4;
    float* h1   = (float*)w;                 w += (size_t)NNODES * 64 * 4;
    float* g    = (float*)w;                 w += (size_t)NGRAPHS * 64 * 4;
    int* deg     = (int*)w;                  w += (size_t)NNODES * 4;
    int* rowstart= (int*)w;                  w += (size_t)NNODES * 4;
    int* cursor  = (int*)w;                  w += (size_t)NNODES * 4;
    int* psum    = (int*)w;                  w += 512 * 4;
    int* esrc    = (int*)w;                  w += (size_t)ET * 4;

    const int BLK = 256;
    const int NB  = (NNODES + 255) / 256;    // 391 <= 512
    int grid_et   = (ET + BLK - 1) / BLK;
    int grid_n    = (NNODES + BLK - 1) / BLK;
    int grid_agg  = (NNODES + 3) / 4;

    // ---- CSR build (once, shared by both layers) ----
    hipMemsetAsync(deg, 0, (size_t)NNODES * 4, stream);
    hipMemsetAsync(cursor, 0, (size_t)NNODES * 4, stream);
    hipMemsetAsync(g, 0, (size_t)NGRAPHS * 64 * 4, stream);
    hist_kernel<<<grid_et, BLK, 0, stream>>>(dstp, deg, E, ET);
    scan_block_kernel<<<NB, 256, 0, stream>>>(deg, rowstart, psum, NNODES);
    scan_partials_kernel<<<1, 512, 0, stream>>>(psum, NB);
    scan_add_kernel<<<NB, 256, 0, stream>>>(rowstart, psum, NNODES);
    scatter_kernel<<<grid_et, BLK, 0, stream>>>(srcp, dstp, rowstart, cursor, esrc, E, ET);

    dim3 gemm_grid(2, (NNODES + BM - 1) / BM);

    // ---- layer 1 ----
    gemm_fused_kernel<<<gemm_grid, BLK, 0, stream>>>(x, W1, (unsigned short*)xwp,
                                                     att_src1, att_dst1, asrc, adst,
                                                     NNODES, 128);
    softmax_kernel<<<grid_n, BLK, 0, stream>>>(rowstart, deg, esrc, asrc, adst, alpha, sinv);
    aggregate_kernel<false><<<grid_agg, BLK, 0, stream>>>(rowstart, deg, esrc, (const float2*)alpha,
                                                          sinv, xwp, b1, h1, nullptr, nullptr);

    // ---- layer 2 ----
    gemm_fused_kernel<<<gemm_grid, BLK, 0, stream>>>(h1, W2, (unsigned short*)xwp,
                                                     att_src2, att_dst2, asrc, adst,
                                                     NNODES, 64);
    softmax_kernel<<<grid_n, BLK, 0, stream>>>(rowstart, deg, esrc, asrc, adst, alpha, sinv);
    aggregate_kernel<true><<<grid_agg, BLK, 0, stream>>>(rowstart, deg, esrc, (const float2*)alpha,
                                                         sinv, xwp, b2, nullptr, batch, g);

    // ---- final FC + log_softmax ----
    final_fc_kernel<<<1, 128, 0, stream>>>(g, Wfc, bfc, out);
}

// Round 5
// 553.148 us; speedup vs baseline: 4.2648x; 1.1275x over previous
//
#include <hip/hip_runtime.h>
#include <cstdint>
#include <cstddef>

#define NNODES 100000
#define NGRAPHS 128
#define NEG_SLOPE 0.2f

static __device__ __forceinline__ unsigned int bf16_rne(float f) {
    unsigned int x = __float_as_uint(f);
    return (x + 0x7fffu + ((x >> 16) & 1u)) >> 16;
}

// ---------- fused GEMM + bf16 pack + attention coefficients ----------
// C = A[M,K] @ B[K,128]; blockIdx.x = head h (64-col half); blockIdx.y = row tile.
// Outputs: xwp16[row*128 + c*2 + h] = bf16(C[row, h*64+c])   (so uint xwp[row*64+c] = {h0,h1})
//          asrc[row*2+h], adst[row*2+h] = dot(C[row, h*64:...], att_src/att_dst[h])
#define BM 64
#define BK 16
__global__ void gemm_fused_kernel(const float* __restrict__ A, const float* __restrict__ B,
                                  unsigned short* __restrict__ xwp16,
                                  const float* __restrict__ att_src, const float* __restrict__ att_dst,
                                  float* __restrict__ asrc, float* __restrict__ adst,
                                  int M, int K) {
    __shared__ float As[BK][BM + 1];
    __shared__ float Bs[BK][64 + 1];
    int tid = threadIdx.x;
    int tx = tid & 15;   // col dir (4 cols each)
    int ty = tid >> 4;   // row dir (4 rows each)
    int row0 = blockIdx.y * BM;
    int h = blockIdx.x;
    int col0 = h * 64;

    float acc[4][4] = {};

    for (int k0 = 0; k0 < K; k0 += BK) {
        {
            int r  = tid >> 2;
            int kb = (tid & 3) * 4;
            int grow = row0 + r;
            #pragma unroll
            for (int u = 0; u < 4; ++u) {
                float v = 0.f;
                if (grow < M) v = A[(size_t)grow * K + k0 + kb + u];
                As[kb + u][r] = v;
            }
        }
        {
            int kk = tid >> 4;
            int cb = (tid & 15) * 4;
            #pragma unroll
            for (int u = 0; u < 4; ++u) {
                Bs[kk][cb + u] = B[(size_t)(k0 + kk) * 128 + col0 + cb + u];
            }
        }
        __syncthreads();
        #pragma unroll
        for (int kk = 0; kk < BK; ++kk) {
            float a[4], b[4];
            #pragma unroll
            for (int i = 0; i < 4; ++i) a[i] = As[kk][ty * 4 + i];
            #pragma unroll
            for (int j = 0; j < 4; ++j) b[j] = Bs[kk][tx * 4 + j];
            #pragma unroll
            for (int i = 0; i < 4; ++i)
                #pragma unroll
                for (int j = 0; j < 4; ++j)
                    acc[i][j] += a[i] * b[j];
        }
        __syncthreads();
    }

    // attention partial dot-products, reduce over the 16 tx lanes
    float ps[4] = {}, pd[4] = {};
    #pragma unroll
    for (int j = 0; j < 4; ++j) {
        float ws = att_src[h * 64 + tx * 4 + j];
        float wd = att_dst[h * 64 + tx * 4 + j];
        #pragma unroll
        for (int i = 0; i < 4; ++i) { ps[i] += acc[i][j] * ws; pd[i] += acc[i][j] * wd; }
    }
    #pragma unroll
    for (int off = 1; off < 16; off <<= 1) {
        #pragma unroll
        for (int i = 0; i < 4; ++i) {
            ps[i] += __shfl_xor(ps[i], off);
            pd[i] += __shfl_xor(pd[i], off);
        }
    }
    if (tx == 0) {
        #pragma unroll
        for (int i = 0; i < 4; ++i) {
            int row = row0 + ty * 4 + i;
            if (row < M) { asrc[row * 2 + h] = ps[i]; adst[row * 2 + h] = pd[i]; }
        }
    }

    // bf16 packed store (interleaved ushort: [row][c][h])
    #pragma unroll
    for (int i = 0; i < 4; ++i) {
        int row = row0 + ty * 4 + i;
        if (row >= M) continue;
        #pragma unroll
        for (int j = 0; j < 4; ++j) {
            int c = tx * 4 + j;
            xwp16[(size_t)row * 128 + c * 2 + h] = (unsigned short)bf16_rne(acc[i][j]);
        }
    }
}

// ---------- CSR build ----------
__global__ void hist_kernel(const int* __restrict__ dst, int* __restrict__ deg, int E, int ET) {
    int e = blockIdx.x * blockDim.x + threadIdx.x;
    if (e >= ET) return;
    int d = (e < E) ? dst[e] : (e - E);
    atomicAdd(&deg[d], 1);
}

__global__ void scan_block_kernel(const int* __restrict__ deg, int* __restrict__ excl,
                                  int* __restrict__ psum, int n) {
    __shared__ int s[256];
    int i = blockIdx.x * 256 + threadIdx.x;
    int v = (i < n) ? deg[i] : 0;
    s[threadIdx.x] = v;
    __syncthreads();
    for (int off = 1; off < 256; off <<= 1) {
        int t = (threadIdx.x >= off) ? s[threadIdx.x - off] : 0;
        __syncthreads();
        s[threadIdx.x] += t;
        __syncthreads();
    }
    if (i < n) excl[i] = s[threadIdx.x] - v;
    if (threadIdx.x == 255) psum[blockIdx.x] = s[255];
}

__global__ void scan_partials_kernel(int* __restrict__ psum, int nb) {
    __shared__ int s[512];
    int v = (threadIdx.x < nb) ? psum[threadIdx.x] : 0;
    s[threadIdx.x] = v;
    __syncthreads();
    for (int off = 1; off < 512; off <<= 1) {
        int t = (threadIdx.x >= off) ? s[threadIdx.x - off] : 0;
        __syncthreads();
        s[threadIdx.x] += t;
        __syncthreads();
    }
    if (threadIdx.x < nb) psum[threadIdx.x] = s[threadIdx.x] - v;   // exclusive
}

__global__ void scan_add_kernel(int* __restrict__ excl, const int* __restrict__ psum, int n) {
    int i = blockIdx.x * 256 + threadIdx.x;
    if (i < n) excl[i] += psum[blockIdx.x];
}

__global__ void scatter_kernel(const int* __restrict__ src, const int* __restrict__ dst,
                               const int* __restrict__ rowstart, int* __restrict__ cursor,
                               int* __restrict__ esrc, int E, int ET) {
    int e = blockIdx.x * blockDim.x + threadIdx.x;
    if (e >= ET) return;
    int s = (e < E) ? src[e] : (e - E);
    int d = (e < E) ? dst[e] : (e - E);
    int slot = rowstart[d] + atomicAdd(&cursor[d], 1);
    esrc[slot] = s;
}

// ---------- fused softmax + gather-aggregate: one WAVE per dst node ----------
// Softmax is shift-invariant: skip the segment-max pass (logits bounded ~|10|,
// exp cannot overflow f32). Single pass: e = exp(leaky(asrc[s]+adst[n])),
// acc += e * xw[s], s += e; normalize by 1/s at the end.
template <bool TO_G>
__global__ void aggregate_kernel(const int* __restrict__ rowstart, const int* __restrict__ deg,
                                 const int* __restrict__ esrc,
                                 const float2* __restrict__ asrc2, const float2* __restrict__ adst2,
                                 const unsigned int* __restrict__ xwp, const float* __restrict__ bias,
                                 float* __restrict__ out, const int* __restrict__ batch,
                                 float* __restrict__ g) {
    int wid  = threadIdx.x >> 6;
    int lane = threadIdx.x & 63;
    int n = blockIdx.x * 4 + wid;
    if (n >= NNODES) return;
    int row = rowstart[n], dg = deg[n];
    float2 ad = adst2[n];
    float acc0 = 0.f, acc1 = 0.f, s0 = 0.f, s1 = 0.f;
    int i = 0;

#define LOADG(k) int sn##k = esrc[row + i + k]; \
                 float2 a##k = asrc2[sn##k]; \
                 unsigned int u##k = xwp[(size_t)sn##k * 64 + lane]
#define FMAG(k)  { float l0 = a##k.x + ad.x; float l1 = a##k.y + ad.y; \
                   l0 = fmaxf(l0, NEG_SLOPE * l0); l1 = fmaxf(l1, NEG_SLOPE * l1); \
                   float e0 = __expf(l0), e1 = __expf(l1); \
                   s0 += e0; s1 += e1; \
                   acc0 += e0 * __uint_as_float(u##k << 16); \
                   acc1 += e1 * __uint_as_float(u##k & 0xffff0000u); }

    for (; i + 8 <= dg; i += 8) {
        LOADG(0); LOADG(1); LOADG(2); LOADG(3);
        LOADG(4); LOADG(5); LOADG(6); LOADG(7);
        FMAG(0); FMAG(1); FMAG(2); FMAG(3);
        FMAG(4); FMAG(5); FMAG(6); FMAG(7);
    }
    for (; i + 2 <= dg; i += 2) {
        LOADG(0); LOADG(1);
        FMAG(0); FMAG(1);
    }
    if (i < dg) {
        LOADG(0);
        FMAG(0);
    }
#undef LOADG
#undef FMAG

    float v = 0.5f * (acc0 / (s0 + 1e-16f) + acc1 / (s1 + 1e-16f)) + bias[lane];
    v = (v > 0.f) ? v : 0.f;
    if (TO_G) atomicAdd(&g[batch[n] * 64 + lane], v);
    else out[(size_t)n * 64 + lane] = v;
}

// ---------- final FC + log_softmax ----------
__global__ void final_fc_kernel(const float* __restrict__ g, const float* __restrict__ Wfc,
                                const float* __restrict__ bfc, float* __restrict__ out) {
    int gi = threadIdx.x;
    if (gi >= NGRAPHS) return;
    float logit[10];
    #pragma unroll
    for (int o = 0; o < 10; ++o) logit[o] = bfc[o];
    for (int c = 0; c < 64; ++c) {
        float gv = g[gi * 64 + c];
        #pragma unroll
        for (int o = 0; o < 10; ++o) logit[o] += gv * Wfc[c * 10 + o];
    }
    float mx = logit[0];
    #pragma unroll
    for (int o = 1; o < 10; ++o) mx = fmaxf(mx, logit[o]);
    float se = 0.f;
    #pragma unroll
    for (int o = 0; o < 10; ++o) se += expf(logit[o] - mx);
    float lse = mx + logf(se);
    #pragma unroll
    for (int o = 0; o < 10; ++o) out[gi * 10 + o] = logit[o] - lse;
}

extern "C" void kernel_launch(void* const* d_in, const int* in_sizes, int n_in,
                              void* d_out, int out_size, void* d_ws, size_t ws_size,
                              hipStream_t stream) {
    const float* x        = (const float*)d_in[0];
    const float* W1       = (const float*)d_in[1];
    const float* att_src1 = (const float*)d_in[2];
    const float* att_dst1 = (const float*)d_in[3];
    const float* b1       = (const float*)d_in[4];
    const float* W2       = (const float*)d_in[5];
    const float* att_src2 = (const float*)d_in[6];
    const float* att_dst2 = (const float*)d_in[7];
    const float* b2       = (const float*)d_in[8];
    const float* Wfc      = (const float*)d_in[9];
    const float* bfc      = (const float*)d_in[10];
    const int*   eidx     = (const int*)d_in[11];
    const int*   batch    = (const int*)d_in[12];
    float* out = (float*)d_out;

    const int E  = in_sizes[11] / 2;
    const int ET = E + NNODES;
    const int* srcp = eidx;
    const int* dstp = eidx + E;

    // workspace layout
    char* w = (char*)d_ws;
    unsigned int* xwp = (unsigned int*)w;    w += (size_t)NNODES * 64 * 4;
    float* asrc = (float*)w;                 w += (size_t)NNODES * 2 * 4;
    float* adst = (float*)w;                 w += (size_t)NNODES * 2 * 4;
    float* h1   = (float*)w;                 w += (size_t)NNODES * 64 * 4;
    float* g    = (float*)w;                 w += (size_t)NGRAPHS * 64 * 4;
    int* deg     = (int*)w;                  w += (size_t)NNODES * 4;
    int* rowstart= (int*)w;                  w += (size_t)NNODES * 4;
    int* cursor  = (int*)w;                  w += (size_t)NNODES * 4;
    int* psum    = (int*)w;                  w += 512 * 4;
    int* esrc    = (int*)w;                  w += (size_t)ET * 4;

    const int BLK = 256;
    const int NB  = (NNODES + 255) / 256;    // 391 <= 512
    int grid_et   = (ET + BLK - 1) / BLK;
    int grid_agg  = (NNODES + 3) / 4;

    // ---- CSR build (once, shared by both layers) ----
    hipMemsetAsync(deg, 0, (size_t)NNODES * 4, stream);
    hipMemsetAsync(cursor, 0, (size_t)NNODES * 4, stream);
    hipMemsetAsync(g, 0, (size_t)NGRAPHS * 64 * 4, stream);
    hist_kernel<<<grid_et, BLK, 0, stream>>>(dstp, deg, E, ET);
    scan_block_kernel<<<NB, 256, 0, stream>>>(deg, rowstart, psum, NNODES);
    scan_partials_kernel<<<1, 512, 0, stream>>>(psum, NB);
    scan_add_kernel<<<NB, 256, 0, stream>>>(rowstart, psum, NNODES);
    scatter_kernel<<<grid_et, BLK, 0, stream>>>(srcp, dstp, rowstart, cursor, esrc, E, ET);

    dim3 gemm_grid(2, (NNODES + BM - 1) / BM);

    // ---- layer 1 ----
    gemm_fused_kernel<<<gemm_grid, BLK, 0, stream>>>(x, W1, (unsigned short*)xwp,
                                                     att_src1, att_dst1, asrc, adst,
                                                     NNODES, 128);
    aggregate_kernel<false><<<grid_agg, BLK, 0, stream>>>(rowstart, deg, esrc,
                                                          (const float2*)asrc, (const float2*)adst,
                                                          xwp, b1, h1, nullptr, nullptr);

    // ---- layer 2 ----
    gemm_fused_kernel<<<gemm_grid, BLK, 0, stream>>>(h1, W2, (unsigned short*)xwp,
                                                     att_src2, att_dst2, asrc, adst,
                                                     NNODES, 64);
    aggregate_kernel<true><<<grid_agg, BLK, 0, stream>>>(rowstart, deg, esrc,
                                                         (const float2*)asrc, (const float2*)adst,
                                                         xwp, b2, nullptr, batch, g);

    // ---- final FC + log_softmax ----
    final_fc_kernel<<<1, 128, 0, stream>>>(g, Wfc, bfc, out);
}

// Round 6
// 485.539 us; speedup vs baseline: 4.8586x; 1.1392x over previous
//
#include <hip/hip_runtime.h>
#include <cstdint>
#include <cstddef>

#define NNODES 100000
#define NGRAPHS 128
#define NEG_SLOPE 0.2f

typedef __attribute__((ext_vector_type(8))) short short8;
typedef __attribute__((ext_vector_type(4))) float f32x4;

static __device__ __forceinline__ unsigned int bf16_rne(float f) {
    unsigned int x = __float_as_uint(f);
    return (x + 0x7fffu + ((x >> 16) & 1u)) >> 16;
}

// ---------- fused MFMA GEMM + bf16 pack + attention coefficients ----------
// C = A[M,K] @ B[K,128]; blockIdx.x = head h (64 cols); blockIdx.y = 64-row tile.
// 256 thr = 4 waves; wave w computes rows 16w..16w+15 x 64 cols via 16x16x32 bf16 MFMA.
// Outputs: xwp16[row*128 + c*2 + h] = bf16(C[row, h*64+c])
//          asrc[row*2+h], adst[row*2+h] = dot(C-row, att_src/att_dst[h])
#define LDS_STRIDE 136   // 128 + 8 ushort pad: keeps 16B align, breaks bank aliasing
template <int K>
__global__ __launch_bounds__(256) void gemm_mfma_kernel(
        const float* __restrict__ A, const float* __restrict__ B,
        unsigned short* __restrict__ xwp16,
        const float* __restrict__ att_src, const float* __restrict__ att_dst,
        float* __restrict__ asrc, float* __restrict__ adst, int M) {
    __shared__ __align__(16) unsigned short A_lds[64 * LDS_STRIDE];
    __shared__ __align__(16) unsigned short B_lds[64 * LDS_STRIDE];
    int tid = threadIdx.x;
    int h = blockIdx.x;
    int row0 = blockIdx.y * 64;
    int col0 = h * 64;

    // stage A tile (64 x K f32 -> bf16), float4 loads
    constexpr int F4PR = K / 4;                 // float4 per row
    #pragma unroll
    for (int i = 0; i < 64 * F4PR / 256; ++i) {
        int idx = tid + i * 256;
        int r = idx / F4PR, c4 = idx % F4PR;
        float4 v = make_float4(0.f, 0.f, 0.f, 0.f);
        int grow = row0 + r;
        if (grow < M) v = *(const float4*)&A[(size_t)grow * K + c4 * 4];
        unsigned short* d = &A_lds[r * LDS_STRIDE + c4 * 4];
        d[0] = (unsigned short)bf16_rne(v.x);
        d[1] = (unsigned short)bf16_rne(v.y);
        d[2] = (unsigned short)bf16_rne(v.z);
        d[3] = (unsigned short)bf16_rne(v.w);
    }
    // stage B transposed: B_lds[c][k] = W[k, col0+c]
    #pragma unroll
    for (int i = 0; i < 64 * K / 256; ++i) {
        int idx = tid + i * 256;
        int c = idx & 63, k = idx >> 6;
        B_lds[c * LDS_STRIDE + k] = (unsigned short)bf16_rne(B[(size_t)k * 128 + col0 + c]);
    }
    __syncthreads();

    int w = tid >> 6, l = tid & 63;
    int lr = l & 15, lg = l >> 4;

    f32x4 acc[4] = {};
    #pragma unroll
    for (int ks = 0; ks < K / 32; ++ks) {
        short8 a = *(const short8*)&A_lds[(16 * w + lr) * LDS_STRIDE + lg * 8 + ks * 32];
        #pragma unroll
        for (int t = 0; t < 4; ++t) {
            short8 b = *(const short8*)&B_lds[(16 * t + lr) * LDS_STRIDE + lg * 8 + ks * 32];
            acc[t] = __builtin_amdgcn_mfma_f32_16x16x32_bf16(a, b, acc[t], 0, 0, 0);
        }
    }

    // epilogue: pack + attention partial dots
    float ps[4] = {}, pd[4] = {};
    #pragma unroll
    for (int t = 0; t < 4; ++t) {
        int c = 16 * t + lr;
        float ws = att_src[h * 64 + c];
        float wd = att_dst[h * 64 + c];
        #pragma unroll
        for (int r = 0; r < 4; ++r) {
            int row = row0 + 16 * w + lg * 4 + r;
            float v = acc[t][r];
            ps[r] += v * ws;
            pd[r] += v * wd;
            if (row < M) xwp16[(size_t)row * 128 + c * 2 + h] = (unsigned short)bf16_rne(v);
        }
    }
    #pragma unroll
    for (int off = 1; off < 16; off <<= 1) {
        #pragma unroll
        for (int r = 0; r < 4; ++r) {
            ps[r] += __shfl_xor(ps[r], off);
            pd[r] += __shfl_xor(pd[r], off);
        }
    }
    if (lr == 0) {
        #pragma unroll
        for (int r = 0; r < 4; ++r) {
            int row = row0 + 16 * w + lg * 4 + r;
            if (row < M) { asrc[row * 2 + h] = ps[r]; adst[row * 2 + h] = pd[r]; }
        }
    }
}

// ---------- CSR build ----------
__global__ void hist_kernel(const int* __restrict__ dst, int* __restrict__ deg, int E, int ET) {
    int e = blockIdx.x * blockDim.x + threadIdx.x;
    if (e >= ET) return;
    int d = (e < E) ? dst[e] : (e - E);
    atomicAdd(&deg[d], 1);
}

__global__ void scan_block_kernel(const int* __restrict__ deg, int* __restrict__ excl,
                                  int* __restrict__ psum, int n) {
    __shared__ int s[256];
    int i = blockIdx.x * 256 + threadIdx.x;
    int v = (i < n) ? deg[i] : 0;
    s[threadIdx.x] = v;
    __syncthreads();
    for (int off = 1; off < 256; off <<= 1) {
        int t = (threadIdx.x >= off) ? s[threadIdx.x - off] : 0;
        __syncthreads();
        s[threadIdx.x] += t;
        __syncthreads();
    }
    if (i < n) excl[i] = s[threadIdx.x] - v;
    if (threadIdx.x == 255) psum[blockIdx.x] = s[255];
}

__global__ void scan_partials_kernel(int* __restrict__ psum, int nb) {
    __shared__ int s[512];
    int v = (threadIdx.x < nb) ? psum[threadIdx.x] : 0;
    s[threadIdx.x] = v;
    __syncthreads();
    for (int off = 1; off < 512; off <<= 1) {
        int t = (threadIdx.x >= off) ? s[threadIdx.x - off] : 0;
        __syncthreads();
        s[threadIdx.x] += t;
        __syncthreads();
    }
    if (threadIdx.x < nb) psum[threadIdx.x] = s[threadIdx.x] - v;   // exclusive
}

__global__ void scan_add_kernel(int* __restrict__ excl, const int* __restrict__ psum, int n) {
    int i = blockIdx.x * 256 + threadIdx.x;
    if (i < n) excl[i] += psum[blockIdx.x];
}

__global__ void scatter_kernel(const int* __restrict__ src, const int* __restrict__ dst,
                               const int* __restrict__ rowstart, int* __restrict__ cursor,
                               int* __restrict__ esrc, int E, int ET) {
    int e = blockIdx.x * blockDim.x + threadIdx.x;
    if (e >= ET) return;
    int s = (e < E) ? src[e] : (e - E);
    int d = (e < E) ? dst[e] : (e - E);
    int slot = rowstart[d] + atomicAdd(&cursor[d], 1);
    esrc[slot] = s;
}

// ---------- fused softmax + gather-aggregate: one WAVE per dst node ----------
template <bool TO_G>
__global__ void aggregate_kernel(const int* __restrict__ rowstart, const int* __restrict__ deg,
                                 const int* __restrict__ esrc,
                                 const float2* __restrict__ asrc2, const float2* __restrict__ adst2,
                                 const unsigned int* __restrict__ xwp, const float* __restrict__ bias,
                                 float* __restrict__ out, const int* __restrict__ batch,
                                 float* __restrict__ g) {
    int wid  = threadIdx.x >> 6;
    int lane = threadIdx.x & 63;
    int n = blockIdx.x * 4 + wid;
    if (n >= NNODES) return;
    int row = rowstart[n], dg = deg[n];
    float2 ad = adst2[n];
    float acc0 = 0.f, acc1 = 0.f, s0 = 0.f, s1 = 0.f;
    int i = 0;

#define LOADG(k) int sn##k = esrc[row + i + k]; \
                 float2 a##k = asrc2[sn##k]; \
                 unsigned int u##k = xwp[(size_t)sn##k * 64 + lane]
#define FMAG(k)  { float l0 = a##k.x + ad.x; float l1 = a##k.y + ad.y; \
                   l0 = fmaxf(l0, NEG_SLOPE * l0); l1 = fmaxf(l1, NEG_SLOPE * l1); \
                   float e0 = __expf(l0), e1 = __expf(l1); \
                   s0 += e0; s1 += e1; \
                   acc0 += e0 * __uint_as_float(u##k << 16); \
                   acc1 += e1 * __uint_as_float(u##k & 0xffff0000u); }

    for (; i + 8 <= dg; i += 8) {
        LOADG(0); LOADG(1); LOADG(2); LOADG(3);
        LOADG(4); LOADG(5); LOADG(6); LOADG(7);
        FMAG(0); FMAG(1); FMAG(2); FMAG(3);
        FMAG(4); FMAG(5); FMAG(6); FMAG(7);
    }
    for (; i + 2 <= dg; i += 2) {
        LOADG(0); LOADG(1);
        FMAG(0); FMAG(1);
    }
    if (i < dg) {
        LOADG(0);
        FMAG(0);
    }
#undef LOADG
#undef FMAG

    float v = 0.5f * (acc0 / (s0 + 1e-16f) + acc1 / (s1 + 1e-16f)) + bias[lane];
    v = (v > 0.f) ? v : 0.f;
    if (TO_G) atomicAdd(&g[batch[n] * 64 + lane], v);
    else out[(size_t)n * 64 + lane] = v;
}

// ---------- final FC + log_softmax ----------
__global__ void final_fc_kernel(const float* __restrict__ g, const float* __restrict__ Wfc,
                                const float* __restrict__ bfc, float* __restrict__ out) {
    int gi = threadIdx.x;
    if (gi >= NGRAPHS) return;
    float logit[10];
    #pragma unroll
    for (int o = 0; o < 10; ++o) logit[o] = bfc[o];
    for (int c = 0; c < 64; ++c) {
        float gv = g[gi * 64 + c];
        #pragma unroll
        for (int o = 0; o < 10; ++o) logit[o] += gv * Wfc[c * 10 + o];
    }
    float mx = logit[0];
    #pragma unroll
    for (int o = 1; o < 10; ++o) mx = fmaxf(mx, logit[o]);
    float se = 0.f;
    #pragma unroll
    for (int o = 0; o < 10; ++o) se += expf(logit[o] - mx);
    float lse = mx + logf(se);
    #pragma unroll
    for (int o = 0; o < 10; ++o) out[gi * 10 + o] = logit[o] - lse;
}

extern "C" void kernel_launch(void* const* d_in, const int* in_sizes, int n_in,
                              void* d_out, int out_size, void* d_ws, size_t ws_size,
                              hipStream_t stream) {
    const float* x        = (const float*)d_in[0];
    const float* W1       = (const float*)d_in[1];
    const float* att_src1 = (const float*)d_in[2];
    const float* att_dst1 = (const float*)d_in[3];
    const float* b1       = (const float*)d_in[4];
    const float* W2       = (const float*)d_in[5];
    const float* att_src2 = (const float*)d_in[6];
    const float* att_dst2 = (const float*)d_in[7];
    const float* b2       = (const float*)d_in[8];
    const float* Wfc      = (const float*)d_in[9];
    const float* bfc      = (const float*)d_in[10];
    const int*   eidx     = (const int*)d_in[11];
    const int*   batch    = (const int*)d_in[12];
    float* out = (float*)d_out;

    const int E  = in_sizes[11] / 2;
    const int ET = E + NNODES;
    const int* srcp = eidx;
    const int* dstp = eidx + E;

    // workspace layout
    char* w = (char*)d_ws;
    unsigned int* xwp = (unsigned int*)w;    w += (size_t)NNODES * 64 * 4;
    float* asrc = (float*)w;                 w += (size_t)NNODES * 2 * 4;
    float* adst = (float*)w;                 w += (size_t)NNODES * 2 * 4;
    float* h1   = (float*)w;                 w += (size_t)NNODES * 64 * 4;
    float* g    = (float*)w;                 w += (size_t)NGRAPHS * 64 * 4;
    int* deg     = (int*)w;                  w += (size_t)NNODES * 4;
    int* rowstart= (int*)w;                  w += (size_t)NNODES * 4;
    int* cursor  = (int*)w;                  w += (size_t)NNODES * 4;
    int* psum    = (int*)w;                  w += 512 * 4;
    int* esrc    = (int*)w;                  w += (size_t)ET * 4;

    const int BLK = 256;
    const int NB  = (NNODES + 255) / 256;    // 391 <= 512
    int grid_et   = (ET + BLK - 1) / BLK;
    int grid_agg  = (NNODES + 3) / 4;

    // ---- CSR build (once, shared by both layers) ----
    hipMemsetAsync(deg, 0, (size_t)NNODES * 4, stream);
    hipMemsetAsync(cursor, 0, (size_t)NNODES * 4, stream);
    hipMemsetAsync(g, 0, (size_t)NGRAPHS * 64 * 4, stream);
    hist_kernel<<<grid_et, BLK, 0, stream>>>(dstp, deg, E, ET);
    scan_block_kernel<<<NB, 256, 0, stream>>>(deg, rowstart, psum, NNODES);
    scan_partials_kernel<<<1, 512, 0, stream>>>(psum, NB);
    scan_add_kernel<<<NB, 256, 0, stream>>>(rowstart, psum, NNODES);
    scatter_kernel<<<grid_et, BLK, 0, stream>>>(srcp, dstp, rowstart, cursor, esrc, E, ET);

    dim3 gemm_grid(2, (NNODES + 63) / 64);

    // ---- layer 1 ----
    gemm_mfma_kernel<128><<<gemm_grid, BLK, 0, stream>>>(x, W1, (unsigned short*)xwp,
                                                         att_src1, att_dst1, asrc, adst, NNODES);
    aggregate_kernel<false><<<grid_agg, BLK, 0, stream>>>(rowstart, deg, esrc,
                                                          (const float2*)asrc, (const float2*)adst,
                                                          xwp, b1, h1, nullptr, nullptr);

    // ---- layer 2 ----
    gemm_mfma_kernel<64><<<gemm_grid, BLK, 0, stream>>>(h1, W2, (unsigned short*)xwp,
                                                        att_src2, att_dst2, asrc, adst, NNODES);
    aggregate_kernel<true><<<grid_agg, BLK, 0, stream>>>(rowstart, deg, esrc,
                                                         (const float2*)asrc, (const float2*)adst,
                                                         xwp, b2, nullptr, batch, g);

    // ---- final FC + log_softmax ----
    final_fc_kernel<<<1, 128, 0, stream>>>(g, Wfc, bfc, out);
}